// Round 5
// baseline (64.977 us; speedup 1.0000x reference)
//
#include <hip/hip_runtime.h>

#define KERNEL_LEN 128
#define INPUT_LEN 1000000
#define PATH_NUM 10
#define L_TOTAL (INPUT_LEN + KERNEL_LEN)
#define NBLOCKS 2048
#define BLOCK_SIZE 256
#define CHUNK 4
#define NPASS 2
#define SLICE (INPUT_LEN / NPASS)   // 500000 floats = 2 MB hot slice per pass

typedef int v4i __attribute__((ext_vector_type(4)));

__global__ __launch_bounds__(BLOCK_SIZE) void dtw_partials(
    const float* __restrict__ kern,
    const float* __restrict__ x,
    const int*   __restrict__ path_k,
    const int*   __restrict__ path_i,
    const int*   __restrict__ path_length,
    const int*   __restrict__ path_num,
    float*       __restrict__ ws)
{
    __shared__ float k_lds[KERNEL_LEN];
    const int tid = threadIdx.x;
    if (tid < KERNEL_LEN) k_lds[tid] = kern[tid];
    __syncthreads();

    const int n = min(path_num[0], PATH_NUM);

    float acc[PATH_NUM];
    #pragma unroll
    for (int p = 0; p < PATH_NUM; ++p) acc[p] = 0.0f;

    const int start  = (blockIdx.x * BLOCK_SIZE + tid) * CHUNK;
    const int stride = NBLOCKS * BLOCK_SIZE * CHUNK;

    // Range-blocked passes: pass r only gathers x[r*SLICE, (r+1)*SLICE).
    // 2MB hot slice stays L2-resident instead of 4MB fighting the stream flow;
    // out-of-range lanes are exec-masked (no memory request issued).
    for (int pass = 0; pass < NPASS; ++pass) {
        const unsigned base = pass * SLICE;
        #pragma unroll
        for (int p = 0; p < PATH_NUM; ++p) {
            if (p < n) {
                const int len  = path_length[p];
                const int len4 = len & ~(CHUNK - 1);
                const int* __restrict__ pk = path_k + (size_t)p * L_TOTAL;
                const int* __restrict__ pi = path_i + (size_t)p * L_TOTAL;

                float a = 0.0f;
                for (int t = start; t < len4; t += stride) {
                    const v4i ik = *reinterpret_cast<const v4i*>(pk + t);
                    const v4i ii = *reinterpret_cast<const v4i*>(pi + t);
                    #pragma unroll
                    for (int j = 0; j < 4; ++j) {
                        const unsigned r = (unsigned)ii[j] - base;
                        if (r < SLICE) {
                            const float d = k_lds[(unsigned)ik[j]] - x[base + r];
                            a = fmaf(d, d, a);
                        }
                    }
                }
                // tail (< 4 elements): block 0 only, same range predicate
                if (blockIdx.x == 0) {
                    const int t = len4 + tid;
                    if (t < len) {
                        const unsigned r = (unsigned)pi[t] - base;
                        if (r < SLICE) {
                            const float d = k_lds[pk[t]] - x[base + r];
                            a = fmaf(d, d, a);
                        }
                    }
                }
                acc[p] += a;
            }
        }
    }

    // block-reduce each path; write per-block partial (NO atomics)
    __shared__ float wsum[PATH_NUM][BLOCK_SIZE / 64];
    const int wave = tid >> 6;
    const int lane = tid & 63;
    #pragma unroll
    for (int p = 0; p < PATH_NUM; ++p) {
        float a = acc[p];
        #pragma unroll
        for (int off = 32; off > 0; off >>= 1)
            a += __shfl_down(a, off, 64);
        if (lane == 0) wsum[p][wave] = a;
    }
    __syncthreads();
    if (tid < PATH_NUM) {
        const float s = wsum[tid][0] + wsum[tid][1] + wsum[tid][2] + wsum[tid][3];
        ws[(size_t)tid * NBLOCKS + blockIdx.x] = (tid < n) ? s : 0.0f;
    }
}

__global__ __launch_bounds__(BLOCK_SIZE) void dtw_reduce(
    const float* __restrict__ ws,
    const int*   __restrict__ path_num,
    float*       __restrict__ out)
{
    const int tid = threadIdx.x;
    const int n = min(path_num[0], PATH_NUM);

    float acc[PATH_NUM];
    #pragma unroll
    for (int p = 0; p < PATH_NUM; ++p) acc[p] = 0.0f;

    for (int t = tid; t < NBLOCKS; t += BLOCK_SIZE) {
        #pragma unroll
        for (int p = 0; p < PATH_NUM; ++p)
            acc[p] += ws[(size_t)p * NBLOCKS + t];
    }

    __shared__ float wsum[PATH_NUM][BLOCK_SIZE / 64];
    const int wave = tid >> 6;
    const int lane = tid & 63;
    #pragma unroll
    for (int p = 0; p < PATH_NUM; ++p) {
        float a = acc[p];
        #pragma unroll
        for (int off = 32; off > 0; off >>= 1)
            a += __shfl_down(a, off, 64);
        if (lane == 0) wsum[p][wave] = a;
    }
    __syncthreads();
    if (tid < PATH_NUM) {
        const float s = wsum[tid][0] + wsum[tid][1] + wsum[tid][2] + wsum[tid][3];
        out[tid] = (tid < n) ? s : 0.0f;   // unconditional write: no memset needed
    }
}

extern "C" void kernel_launch(void* const* d_in, const int* in_sizes, int n_in,
                              void* d_out, int out_size, void* d_ws, size_t ws_size,
                              hipStream_t stream) {
    const float* kern        = (const float*)d_in[0];
    const float* x           = (const float*)d_in[1];
    const int*   path_k      = (const int*)d_in[2];
    const int*   path_i      = (const int*)d_in[3];
    const int*   path_length = (const int*)d_in[4];
    const int*   path_num    = (const int*)d_in[5];
    float*       out         = (float*)d_out;
    float*       partials    = (float*)d_ws;   // 2048*10*4 = 80 KB << ws_size

    dtw_partials<<<dim3(NBLOCKS), dim3(BLOCK_SIZE), 0, stream>>>(
        kern, x, path_k, path_i, path_length, path_num, partials);
    dtw_reduce<<<dim3(1), dim3(BLOCK_SIZE), 0, stream>>>(
        partials, path_num, out);
}